// Round 14
// baseline (365.756 us; speedup 1.0000x reference)
//
#include <hip/hip_runtime.h>
#include <math.h>

// Chamfer distance, B=4, N=M=8192, D=3, fp32 — fused MFMA, no LDS staging.
//
// t = q.r - c_r via v_mfma_f32_32x32x16_f16, fp16 hi/lo split (HW-verified
// rounds 9/10/12, absmax 0.0):
//   A (ref):   k0..7 = [h0,h1,h2,l0,l1,l2,h0,h1], k8..15 = [h2,-chi,-clo,0..]
//   B (query): k0..7 = [hq0,hq1,hq2,hq0,hq1,hq2,lq0,lq1], k8..15 = [lq2,1,1,0..]
//   dot = (h+l).(hq+lq) - l.lq - c   (|l.lq| <= ~3e-6)
// min_r d^2/2 = cq - max_r t.  A row = lane&31, k-half = lane>>5;
// C col = lane&31, row = (reg&3)+8*(reg>>2)+4*(lane>>5).
//
// Round-12 lessons:
//  * each graph node costs ~5-10 us in replay gaps -> minimize nodes (2).
//  * ref cloud is 96 KB = L2-resident; LDS staging is pure overhead
//    (Common-mistake #7). A-frag lane gathers its ref DIRECTLY from
//    global (L1/L2 hit), converts in-register. No barriers in main loop.
//  * occupancy first (r11): 512 blocks x 16 waves = 8192 waves machine-wide.
//
// Block = 128 queries x ALL refs; wave w owns refs [w*512,(w+1)*512).
// Cross-wave min combine via LDS atomicMin (128 uint slots, d^2/2 bits,
// non-negative so uint order == float order), then sqrt+mean+one atomicAdd.
// Graph: memset(4B out) + kernel. Workspace unused.
// ~41 us of dur_us is the harness 0xAA re-poison of the 256 MB ws — floor.

typedef __attribute__((ext_vector_type(8)))  _Float16 f16x8;
typedef __attribute__((ext_vector_type(16))) float    f32x16;

constexpr int TPB   = 1024;           // 16 waves
constexpr int NPTS  = 8192;           // N == M
constexpr int NB    = 4;              // batch
constexpr int QPB   = 128;            // queries per block (4 col-frags)
constexpr int RPW   = 512;            // refs per wave
constexpr int TILES = RPW / 32;       // 16 MFMA ref-tiles per wave

__device__ inline float max3f(float a, float b, float c) {
    return fmaxf(fmaxf(a, b), c);   // clang fuses to v_max3_f32
}

__device__ inline float merge16(float run, f32x16 v) {
    const float w0 = max3f(v[0],  v[1],  v[2]);
    const float w1 = max3f(v[3],  v[4],  v[5]);
    const float w2 = max3f(v[6],  v[7],  v[8]);
    const float w3 = max3f(v[9],  v[10], v[11]);
    const float w4 = max3f(v[12], v[13], v[14]);
    const float x0 = max3f(w0, w1, v[15]);
    const float x1 = max3f(w2, w3, w4);
    return max3f(run, x0, x1);
}

__device__ inline f16x8 make_qfrag(float x, float y, float z, int half) {
    const _Float16 hx = (_Float16)x, hy = (_Float16)y, hz = (_Float16)z;
    const _Float16 lx = (_Float16)(x - (float)hx);
    const _Float16 ly = (_Float16)(y - (float)hy);
    const _Float16 lz = (_Float16)(z - (float)hz);
    const f16x8 f0 = (f16x8){hx, hy, hz, hx, hy, hz, lx, ly};
    const f16x8 f1 = (f16x8){lz, (_Float16)1.0f, (_Float16)1.0f, 0, 0, 0, 0, 0};
    return half ? f1 : f0;
}

__device__ inline f16x8 make_afrag(float x, float y, float z, int half) {
    const _Float16 hx = (_Float16)x, hy = (_Float16)y, hz = (_Float16)z;
    const _Float16 lx = (_Float16)(x - (float)hx);
    const _Float16 ly = (_Float16)(y - (float)hy);
    const _Float16 lz = (_Float16)(z - (float)hz);
    const float c = 0.5f * fmaf(z, z, fmaf(y, y, x * x));
    const _Float16 chi = (_Float16)c;
    const _Float16 clo = (_Float16)(c - (float)chi);
    const f16x8 f0 = (f16x8){hx, hy, hz, lx, ly, lz, hx, hy};
    const f16x8 f1 = (f16x8){hz, -chi, -clo, 0, 0, 0, 0, 0};
    return half ? f1 : f0;
}

__global__ __launch_bounds__(TPB) void chamfer_fused(
    const float* __restrict__ inp, const float* __restrict__ tgt,
    float* __restrict__ out)
{
    const int z   = blockIdx.y;        // dir*4 + b
    const int dir = z >> 2, b = z & 3;
    const float* Q = (dir ? tgt : inp) + (size_t)b * NPTS * 3;
    const float* R = (dir ? inp : tgt) + (size_t)b * NPTS * 3;

    const int tid  = threadIdx.x;
    const int w    = tid >> 6;          // wave = ref-slice owner
    const int lane = tid & 63;
    const int half = lane >> 5;
    const int col  = lane & 31;

    // 4 query column-fragments (128 queries per block, same for all waves)
    float cq[4];
    f16x8 bq[4];
#pragma unroll
    for (int f = 0; f < 4; ++f) {
        const int q = blockIdx.x * QPB + f * 32 + col;
        const float x = Q[q * 3 + 0], y = Q[q * 3 + 1], zc = Q[q * 3 + 2];
        cq[f] = 0.5f * fmaf(zc, zc, fmaf(y, y, x * x));
        bq[f] = make_qfrag(x, y, zc, half);
    }

    const f32x16 zf = (f32x16)0.0f;     // persistent zero C-operand
    float run[4] = {-3.4e38f, -3.4e38f, -3.4e38f, -3.4e38f};

    // wave-private ref slice, gathered straight from L1/L2 (96 KB cloud),
    // converted in-register; next tile's point prefetched under the MFMAs.
    const int r0 = w * RPW + col;
    float rx = R[r0 * 3 + 0], ry = R[r0 * 3 + 1], rz = R[r0 * 3 + 2];
#pragma unroll 4
    for (int t = 0; t < TILES; ++t) {
        float nx = 0.0f, ny = 0.0f, nz = 0.0f;
        if (t + 1 < TILES) {
            const int rn = r0 + (t + 1) * 32;
            nx = R[rn * 3 + 0]; ny = R[rn * 3 + 1]; nz = R[rn * 3 + 2];
        }
        const f16x8 a = make_afrag(rx, ry, rz, half);
#pragma unroll
        for (int f = 0; f < 4; ++f) {
            const f32x16 acc =
                __builtin_amdgcn_mfma_f32_32x32x16_f16(a, bq[f], zf, 0, 0, 0);
            run[f] = merge16(run[f], acc);
        }
        rx = nx; ry = ny; rz = nz;
    }

    // cross-wave combine: LDS atomicMin on d^2/2 bit patterns (>=0).
    // Each lane covers half the ref-rows of its tiles (C rows
    // (reg&3)+8*(reg>>2)+4*half) -> both lanes of a (col,f) pair and all
    // 16 waves atomicMin into the same query slot.
    __shared__ unsigned int smin[QPB];
    __shared__ float psum[2];
    if (tid < QPB) smin[tid] = 0xFFFFFFFFu;
    __syncthreads();
#pragma unroll
    for (int f = 0; f < 4; ++f) {
        const float sval = fmaxf(cq[f] - run[f], 0.0f);
        atomicMin(&smin[f * 32 + col], __float_as_uint(sval));
    }
    __syncthreads();
    if (tid < QPB) {   // waves 0-1: sqrt + mean + 2-wave partial sums
        const float v = __uint_as_float(smin[tid]);
        float term = sqrtf(2.0f * v) * (1.0f / NPTS);
#pragma unroll
        for (int off = 32; off > 0; off >>= 1)
            term += __shfl_down(term, off, 64);
        if ((tid & 63) == 0) psum[tid >> 6] = term;
    }
    __syncthreads();
    if (tid == 0) atomicAdd(out, psum[0] + psum[1]);
}

// ---- fallback (proven round-3 VALU path, general shapes) ----
__global__ __launch_bounds__(256) void chamfer_nn_valu(
    const float* __restrict__ A, const float* __restrict__ Bp,
    unsigned int* __restrict__ minA, unsigned int* __restrict__ minB,
    int N, int M, int B)
{
    const int bz = blockIdx.z, b = bz % B, dir = bz / B;
    const float* Q = dir ? Bp : A;
    const float* R = dir ? A : Bp;
    unsigned int* om = dir ? minB : minA;
    const int NQ = dir ? M : N, NR = dir ? N : M;
    const int mSlice = NR / gridDim.y;
    const int tid = threadIdx.x;
    const int nBase = blockIdx.x * (256 * 4);
    const int mStart = blockIdx.y * mSlice;
    const float* qb = Q + (size_t)b * NQ * 3;
    const float* rb = R + (size_t)b * NR * 3;
    float qx[4], qy[4], qz[4], dmax[4];
#pragma unroll
    for (int k = 0; k < 4; ++k) {
        const int n = nBase + tid + k * 256;
        qx[k] = qb[n * 3]; qy[k] = qb[n * 3 + 1]; qz[k] = qb[n * 3 + 2];
        dmax[k] = -3.4e38f;
    }
    __shared__ float4 tgtl[256];
    for (int m0 = mStart; m0 < mStart + mSlice; m0 += 256) {
        __syncthreads();
        {
            const float* src = rb + (size_t)(m0 + tid) * 3;
            const float rx = src[0], ry = src[1], rz = src[2];
            tgtl[tid] = make_float4(rx, ry, rz,
                -0.5f * fmaf(rz, rz, fmaf(ry, ry, rx * rx)));
        }
        __syncthreads();
#pragma unroll 2
        for (int j = 0; j < 256; j += 2) {
            const float4 r0 = tgtl[j], r1 = tgtl[j + 1];
#pragma unroll
            for (int k = 0; k < 4; ++k) {
                const float t0 = fmaf(qz[k], r0.z, fmaf(qy[k], r0.y, fmaf(qx[k], r0.x, r0.w)));
                const float t1 = fmaf(qz[k], r1.z, fmaf(qy[k], r1.y, fmaf(qx[k], r1.x, r1.w)));
                dmax[k] = max3f(dmax[k], t0, t1);
            }
        }
    }
#pragma unroll
    for (int k = 0; k < 4; ++k) {
        const int n = nBase + tid + k * 256;
        const float c = 0.5f * fmaf(qz[k], qz[k], fmaf(qy[k], qy[k], qx[k] * qx[k]));
        atomicMin(&om[(size_t)b * NQ + n], __float_as_uint(fmaxf(c - dmax[k], 0.0f)));
    }
}

__global__ __launch_bounds__(256) void chamfer_reduce(
    const unsigned int* __restrict__ mins, int nA, int nTotal,
    float scaleA, float scaleB, float* __restrict__ out)
{
    float s = 0.0f;
    for (int i = blockIdx.x * blockDim.x + threadIdx.x; i < nTotal;
         i += gridDim.x * blockDim.x) {
        s += sqrtf(2.0f * __uint_as_float(mins[i])) * (i < nA ? scaleA : scaleB);
    }
#pragma unroll
    for (int off = 32; off > 0; off >>= 1) s += __shfl_down(s, off, 64);
    __shared__ float wsum[4];
    const int lane = threadIdx.x & 63, wid = threadIdx.x >> 6;
    if (lane == 0) wsum[wid] = s;
    __syncthreads();
    if (threadIdx.x == 0) atomicAdd(out, wsum[0] + wsum[1] + wsum[2] + wsum[3]);
}

extern "C" void kernel_launch(void* const* d_in, const int* in_sizes, int n_in,
                              void* d_out, int out_size, void* d_ws, size_t ws_size,
                              hipStream_t stream) {
    const float* inp = (const float*)d_in[0];  // [B, N, 3]
    const float* tgt = (const float*)d_in[1];  // [B, M, 3]
    float* out = (float*)d_out;

    const int B = 4, D = 3;
    const int N = in_sizes[0] / (B * D);
    const int M = in_sizes[1] / (B * D);

    if (N == NPTS && M == NPTS && B == NB) {
        // ---- fused MFMA path: 2 graph nodes, no workspace ----
        hipMemsetAsync(d_out, 0, sizeof(float), stream);
        dim3 grid(NPTS / QPB, 2 * NB);         // (64, 8) = 512 blocks
        chamfer_fused<<<grid, TPB, 0, stream>>>(inp, tgt, out);
    } else {
        // ---- fallback: proven sentinel/atomic VALU path ----
        unsigned int* min_in  = (unsigned int*)d_ws;
        unsigned int* min_tgt = min_in + (size_t)B * N;
        hipMemsetAsync(d_ws, 0xFF,
                       (size_t)(B * N + B * M) * sizeof(unsigned int), stream);
        hipMemsetAsync(d_out, 0, sizeof(float), stream);
        dim3 grid(N / (256 * 4), 32, 2 * B);
        chamfer_nn_valu<<<grid, 256, 0, stream>>>(inp, tgt, min_in, min_tgt, N, M, B);
        chamfer_reduce<<<dim3(64), 256, 0, stream>>>(
            min_in, B * N, B * (N + M), 1.0f / N, 1.0f / M, out);
    }
}

// Round 15
// 97.915 us; speedup vs baseline: 3.7354x; 3.7354x over previous
//
#include <hip/hip_runtime.h>
#include <math.h>

// Chamfer distance, B=4, N=M=8192, D=3, fp32 — fused MFMA, no LDS staging.
//
// t = q.r - c_r via v_mfma_f32_32x32x16_f16, fp16 hi/lo split (HW-verified
// rounds 9/10/12, absmax 0.0):
//   A (ref):   k0..7 = [h0,h1,h2,l0,l1,l2,h0,h1], k8..15 = [h2,-chi,-clo,0..]
//   B (query): k0..7 = [hq0,hq1,hq2,hq0,hq1,hq2,lq0,lq1], k8..15 = [lq2,1,1,0..]
//   dot = (h+l).(hq+lq) - l.lq - c   (|l.lq| <= ~3e-6)
// min_r d^2/2 = cq - max_r t.  A row = lane&31, k-half = lane>>5;
// C col = lane&31, row = (reg&3)+8*(reg>>2)+4*(lane>>5).
//
// Round-14 lesson (round-5 repeat): TPB=1024 capped VGPR at 64 -> scratch
// spill (1.5 GB/dispatch traffic, 366 us). Spill tell = low VGPR + huge
// FETCH/WRITE. Fix: TPB=256 (VGPR ceiling 128) + 2 q-frags/wave (~60-70
// live regs). 1024 blocks x 4 waves = 4 waves/SIMD (r11: 2 waves/SIMD is
// latency-bound; r12: occupancy first).
// Ref cloud is 96 KB = L2-resident -> per-lane gather, no LDS staging, no
// main-loop barriers (Common-mistake #7). 2 graph nodes (r12: ~5-10 us/node).
// ~41 us of dur_us is the harness 0xAA re-poison of the 256 MB ws — floor.

typedef __attribute__((ext_vector_type(8)))  _Float16 f16x8;
typedef __attribute__((ext_vector_type(16))) float    f32x16;

constexpr int TPB   = 256;            // 4 waves
constexpr int NPTS  = 8192;           // N == M
constexpr int NB    = 4;              // batch
constexpr int QPB   = 64;             // queries per block (2 col-frags)
constexpr int RPW   = 2048;           // refs per wave (4 waves cover 8192)
constexpr int TILES = RPW / 32;       // 64 MFMA ref-tiles per wave

__device__ inline float max3f(float a, float b, float c) {
    return fmaxf(fmaxf(a, b), c);   // clang fuses to v_max3_f32
}

__device__ inline float merge16(float run, f32x16 v) {
    const float w0 = max3f(v[0],  v[1],  v[2]);
    const float w1 = max3f(v[3],  v[4],  v[5]);
    const float w2 = max3f(v[6],  v[7],  v[8]);
    const float w3 = max3f(v[9],  v[10], v[11]);
    const float w4 = max3f(v[12], v[13], v[14]);
    const float x0 = max3f(w0, w1, v[15]);
    const float x1 = max3f(w2, w3, w4);
    return max3f(run, x0, x1);
}

__device__ inline f16x8 make_qfrag(float x, float y, float z, int half) {
    const _Float16 hx = (_Float16)x, hy = (_Float16)y, hz = (_Float16)z;
    const _Float16 lx = (_Float16)(x - (float)hx);
    const _Float16 ly = (_Float16)(y - (float)hy);
    const _Float16 lz = (_Float16)(z - (float)hz);
    const f16x8 f0 = (f16x8){hx, hy, hz, hx, hy, hz, lx, ly};
    const f16x8 f1 = (f16x8){lz, (_Float16)1.0f, (_Float16)1.0f, 0, 0, 0, 0, 0};
    return half ? f1 : f0;
}

__device__ inline f16x8 make_afrag(float x, float y, float z, int half) {
    const _Float16 hx = (_Float16)x, hy = (_Float16)y, hz = (_Float16)z;
    const _Float16 lx = (_Float16)(x - (float)hx);
    const _Float16 ly = (_Float16)(y - (float)hy);
    const _Float16 lz = (_Float16)(z - (float)hz);
    const float c = 0.5f * fmaf(z, z, fmaf(y, y, x * x));
    const _Float16 chi = (_Float16)c;
    const _Float16 clo = (_Float16)(c - (float)chi);
    const f16x8 f0 = (f16x8){hx, hy, hz, lx, ly, lz, hx, hy};
    const f16x8 f1 = (f16x8){hz, -chi, -clo, 0, 0, 0, 0, 0};
    return half ? f1 : f0;
}

__global__ __launch_bounds__(TPB) void chamfer_fused(
    const float* __restrict__ inp, const float* __restrict__ tgt,
    float* __restrict__ out)
{
    const int z   = blockIdx.y;        // dir*4 + b
    const int dir = z >> 2, b = z & 3;
    const float* Q = (dir ? tgt : inp) + (size_t)b * NPTS * 3;
    const float* R = (dir ? inp : tgt) + (size_t)b * NPTS * 3;

    const int tid  = threadIdx.x;
    const int w    = tid >> 6;          // wave = ref-slice owner
    const int lane = tid & 63;
    const int half = lane >> 5;
    const int col  = lane & 31;

    // 2 query column-fragments (64 queries per block, same for all waves)
    float cq[2];
    f16x8 bq[2];
#pragma unroll
    for (int f = 0; f < 2; ++f) {
        const int q = blockIdx.x * QPB + f * 32 + col;
        const float x = Q[q * 3 + 0], y = Q[q * 3 + 1], zc = Q[q * 3 + 2];
        cq[f] = 0.5f * fmaf(zc, zc, fmaf(y, y, x * x));
        bq[f] = make_qfrag(x, y, zc, half);
    }

    const f32x16 zf = (f32x16)0.0f;     // persistent zero C-operand
    float run[2] = {-3.4e38f, -3.4e38f};

    // wave-private ref slice, gathered straight from L1/L2 (96 KB cloud),
    // converted in-register; next tile's point prefetched under the MFMAs.
    const int r0 = w * RPW + col;
    float rx = R[r0 * 3 + 0], ry = R[r0 * 3 + 1], rz = R[r0 * 3 + 2];
#pragma unroll 4
    for (int t = 0; t < TILES; ++t) {
        float nx = 0.0f, ny = 0.0f, nz = 0.0f;
        if (t + 1 < TILES) {
            const int rn = r0 + (t + 1) * 32;
            nx = R[rn * 3 + 0]; ny = R[rn * 3 + 1]; nz = R[rn * 3 + 2];
        }
        const f16x8 a = make_afrag(rx, ry, rz, half);
#pragma unroll
        for (int f = 0; f < 2; ++f) {
            const f32x16 acc =
                __builtin_amdgcn_mfma_f32_32x32x16_f16(a, bq[f], zf, 0, 0, 0);
            run[f] = merge16(run[f], acc);
        }
        rx = nx; ry = ny; rz = nz;
    }

    // cross-wave combine: LDS atomicMin on d^2/2 bit patterns (>=0 so uint
    // order == float order). 4 waves x 2 halves atomicMin per (f,col) slot.
    __shared__ unsigned int smin[QPB];
    if (tid < QPB) smin[tid] = 0xFFFFFFFFu;
    __syncthreads();
#pragma unroll
    for (int f = 0; f < 2; ++f) {
        const float sval = fmaxf(cq[f] - run[f], 0.0f);
        atomicMin(&smin[f * 32 + col], __float_as_uint(sval));
    }
    __syncthreads();
    if (tid < 64) {   // wave 0: sqrt + mean + block sum + one atomicAdd
        const float v = __uint_as_float(smin[tid]);
        float term = sqrtf(2.0f * v) * (1.0f / NPTS);
#pragma unroll
        for (int off = 32; off > 0; off >>= 1)
            term += __shfl_down(term, off, 64);
        if (tid == 0) atomicAdd(out, term);
    }
}

// ---- fallback (proven round-3 VALU path, general shapes) ----
__global__ __launch_bounds__(256) void chamfer_nn_valu(
    const float* __restrict__ A, const float* __restrict__ Bp,
    unsigned int* __restrict__ minA, unsigned int* __restrict__ minB,
    int N, int M, int B)
{
    const int bz = blockIdx.z, b = bz % B, dir = bz / B;
    const float* Q = dir ? Bp : A;
    const float* R = dir ? A : Bp;
    unsigned int* om = dir ? minB : minA;
    const int NQ = dir ? M : N, NR = dir ? N : M;
    const int mSlice = NR / gridDim.y;
    const int tid = threadIdx.x;
    const int nBase = blockIdx.x * (256 * 4);
    const int mStart = blockIdx.y * mSlice;
    const float* qb = Q + (size_t)b * NQ * 3;
    const float* rb = R + (size_t)b * NR * 3;
    float qx[4], qy[4], qz[4], dmax[4];
#pragma unroll
    for (int k = 0; k < 4; ++k) {
        const int n = nBase + tid + k * 256;
        qx[k] = qb[n * 3]; qy[k] = qb[n * 3 + 1]; qz[k] = qb[n * 3 + 2];
        dmax[k] = -3.4e38f;
    }
    __shared__ float4 tgtl[256];
    for (int m0 = mStart; m0 < mStart + mSlice; m0 += 256) {
        __syncthreads();
        {
            const float* src = rb + (size_t)(m0 + tid) * 3;
            const float rx = src[0], ry = src[1], rz = src[2];
            tgtl[tid] = make_float4(rx, ry, rz,
                -0.5f * fmaf(rz, rz, fmaf(ry, ry, rx * rx)));
        }
        __syncthreads();
#pragma unroll 2
        for (int j = 0; j < 256; j += 2) {
            const float4 r0 = tgtl[j], r1 = tgtl[j + 1];
#pragma unroll
            for (int k = 0; k < 4; ++k) {
                const float t0 = fmaf(qz[k], r0.z, fmaf(qy[k], r0.y, fmaf(qx[k], r0.x, r0.w)));
                const float t1 = fmaf(qz[k], r1.z, fmaf(qy[k], r1.y, fmaf(qx[k], r1.x, r1.w)));
                dmax[k] = max3f(dmax[k], t0, t1);
            }
        }
    }
#pragma unroll
    for (int k = 0; k < 4; ++k) {
        const int n = nBase + tid + k * 256;
        const float c = 0.5f * fmaf(qz[k], qz[k], fmaf(qy[k], qy[k], qx[k] * qx[k]));
        atomicMin(&om[(size_t)b * NQ + n], __float_as_uint(fmaxf(c - dmax[k], 0.0f)));
    }
}

__global__ __launch_bounds__(256) void chamfer_reduce(
    const unsigned int* __restrict__ mins, int nA, int nTotal,
    float scaleA, float scaleB, float* __restrict__ out)
{
    float s = 0.0f;
    for (int i = blockIdx.x * blockDim.x + threadIdx.x; i < nTotal;
         i += gridDim.x * blockDim.x) {
        s += sqrtf(2.0f * __uint_as_float(mins[i])) * (i < nA ? scaleA : scaleB);
    }
#pragma unroll
    for (int off = 32; off > 0; off >>= 1) s += __shfl_down(s, off, 64);
    __shared__ float wsum[4];
    const int lane = threadIdx.x & 63, wid = threadIdx.x >> 6;
    if (lane == 0) wsum[wid] = s;
    __syncthreads();
    if (threadIdx.x == 0) atomicAdd(out, wsum[0] + wsum[1] + wsum[2] + wsum[3]);
}

extern "C" void kernel_launch(void* const* d_in, const int* in_sizes, int n_in,
                              void* d_out, int out_size, void* d_ws, size_t ws_size,
                              hipStream_t stream) {
    const float* inp = (const float*)d_in[0];  // [B, N, 3]
    const float* tgt = (const float*)d_in[1];  // [B, M, 3]
    float* out = (float*)d_out;

    const int B = 4, D = 3;
    const int N = in_sizes[0] / (B * D);
    const int M = in_sizes[1] / (B * D);

    if (N == NPTS && M == NPTS && B == NB) {
        // ---- fused MFMA path: 2 graph nodes, no workspace ----
        hipMemsetAsync(d_out, 0, sizeof(float), stream);
        dim3 grid(NPTS / QPB, 2 * NB);         // (128, 8) = 1024 blocks
        chamfer_fused<<<grid, TPB, 0, stream>>>(inp, tgt, out);
    } else {
        // ---- fallback: proven sentinel/atomic VALU path ----
        unsigned int* min_in  = (unsigned int*)d_ws;
        unsigned int* min_tgt = min_in + (size_t)B * N;
        hipMemsetAsync(d_ws, 0xFF,
                       (size_t)(B * N + B * M) * sizeof(unsigned int), stream);
        hipMemsetAsync(d_out, 0, sizeof(float), stream);
        dim3 grid(N / (256 * 4), 32, 2 * B);
        chamfer_nn_valu<<<grid, 256, 0, stream>>>(inp, tgt, min_in, min_tgt, N, M, B);
        chamfer_reduce<<<dim3(64), 256, 0, stream>>>(
            min_in, B * N, B * (N + M), 1.0f / N, 1.0f / M, out);
    }
}

// Round 16
// 78.965 us; speedup vs baseline: 4.6319x; 1.2400x over previous
//
#include <hip/hip_runtime.h>
#include <math.h>

// Chamfer distance, B=4, N=M=8192, D=3, fp32 — prep-once MFMA + direct loads.
//
// t = q.r - c_r via v_mfma_f32_32x32x16_f16, fp16 hi/lo split (HW-verified
// rounds 9/10/12/15, absmax 0.0):
//   A (ref):   k0..7 = [h0,h1,h2,l0,l1,l2,h0,h1], k8..15 = [h2,-chi,-clo,0..]
//   B (query): k0..7 = [hq0,hq1,hq2,hq0,hq1,hq2,lq0,lq1], k8..15 = [lq2,1,1,0..]
//   dot = (h+l).(hq+lq) - l.lq - c   (|l.lq| <= ~3e-6)
// min_r d^2/2 = cq - max_r t.  A row = lane&31, k-half = lane>>5;
// C col = lane&31, row = (reg&3)+8*(reg>>2)+4*(lane>>5).
//
// Round-15 lesson: in-register afrag conversion (~30 VALU) repeated per
// query-block = 8.4M conversions -> VALU-bound at 62%, 49 us. Only 131k
// unique fragments exist. Fix = r9's prep kernel (convert ONCE into 2 MB
// ws, L2-resident) + per-lane coalesced 16B frag loads in the NN kernel
// (frag[tile*64+lane] -> lane-linear, 1KB/wave). No LDS staging, no
// main-loop barriers. prep also zeroes out -> still 2 graph nodes.
// Occupancy: 512 blocks x 8 waves = 4096 waves = 4/SIMD (r11: 2 is
// latency-bound; r14: TPB>512 VGPR-caps into spill).
// ~41 us of dur_us is the harness 0xAA re-poison of the 256 MB ws — floor.

typedef __attribute__((ext_vector_type(8)))  _Float16 f16x8;
typedef __attribute__((ext_vector_type(16))) float    f32x16;

constexpr int TPB   = 512;            // 8 waves
constexpr int NPTS  = 8192;           // N == M
constexpr int NB    = 4;              // batch
constexpr int QPB   = 128;            // queries per block (4 col-frags)
constexpr int RPW   = 1024;           // refs per wave (8 waves cover 8192)
constexpr int TILES = RPW / 32;       // 32 MFMA ref-tiles per wave
constexpr int FPC   = 16384;          // fragments per (cloud,b): 256 tiles x 64

__device__ inline float max3f(float a, float b, float c) {
    return fmaxf(fmaxf(a, b), c);   // clang fuses to v_max3_f32
}

__device__ inline float merge16(float run, f32x16 v) {
    const float w0 = max3f(v[0],  v[1],  v[2]);
    const float w1 = max3f(v[3],  v[4],  v[5]);
    const float w2 = max3f(v[6],  v[7],  v[8]);
    const float w3 = max3f(v[9],  v[10], v[11]);
    const float w4 = max3f(v[12], v[13], v[14]);
    const float x0 = max3f(w0, w1, v[15]);
    const float x1 = max3f(w2, w3, w4);
    return max3f(run, x0, x1);
}

__device__ inline f16x8 make_qfrag(float x, float y, float z, int half) {
    const _Float16 hx = (_Float16)x, hy = (_Float16)y, hz = (_Float16)z;
    const _Float16 lx = (_Float16)(x - (float)hx);
    const _Float16 ly = (_Float16)(y - (float)hy);
    const _Float16 lz = (_Float16)(z - (float)hz);
    const f16x8 f0 = (f16x8){hx, hy, hz, hx, hy, hz, lx, ly};
    const f16x8 f1 = (f16x8){lz, (_Float16)1.0f, (_Float16)1.0f, 0, 0, 0, 0, 0};
    return half ? f1 : f0;
}

// ---- prep: pack ref fragments [cloudb(8)][tile(256)][half(2)][rl(32)],
// 16B each; also zeroes out[0] (r9-verified) ----
__global__ __launch_bounds__(256) void prep_frags(
    const float* __restrict__ inp, const float* __restrict__ tgt,
    f16x8* __restrict__ frag, float* __restrict__ out)
{
    const int idx = blockIdx.x * 256 + threadIdx.x;  // 0..131071
    if (idx == 0) *out = 0.0f;                       // NN runs stream-after
    const int rl    = idx & 31;
    const int half  = (idx >> 5) & 1;
    const int tile  = (idx >> 6) & 255;
    const int cb    = idx >> 14;       // cloud*4 + b
    const int cloud = cb >> 2;
    const int b     = cb & 3;
    const int r     = tile * 32 + rl;
    const float* src = (cloud ? tgt : inp) + ((size_t)b * NPTS + r) * 3;
    const float x = src[0], y = src[1], z = src[2];
    const _Float16 hx = (_Float16)x, hy = (_Float16)y, hz = (_Float16)z;
    const _Float16 lx = (_Float16)(x - (float)hx);
    const _Float16 ly = (_Float16)(y - (float)hy);
    const _Float16 lz = (_Float16)(z - (float)hz);
    const float c = 0.5f * (x * x + y * y + z * z);
    const _Float16 chi = (_Float16)c;
    const _Float16 clo = (_Float16)(c - (float)chi);
    f16x8 f;
    if (half == 0) f = (f16x8){hx, hy, hz, lx, ly, lz, hx, hy};
    else           f = (f16x8){hz, -chi, -clo, 0, 0, 0, 0, 0};
    frag[idx] = f;
}

// ---- NN: 128 queries/block, wave w scans refs [w*1024,(w+1)*1024) via
// direct coalesced frag loads (2 MB buffer, L2-resident) ----
__global__ __launch_bounds__(TPB) void chamfer_nn(
    const float* __restrict__ inp, const float* __restrict__ tgt,
    const f16x8* __restrict__ frag, float* __restrict__ out)
{
    const int z   = blockIdx.y;        // dir*4 + b
    const int dir = z >> 2, b = z & 3;
    const float* Q = (dir ? tgt : inp) + (size_t)b * NPTS * 3;
    const int refcloud = dir ? 0 : 1;
    const f16x8* fr = frag + (size_t)(refcloud * 4 + b) * FPC;

    const int tid  = threadIdx.x;
    const int w    = tid >> 6;          // wave = ref-slice owner
    const int lane = tid & 63;
    const int half = lane >> 5;
    const int col  = lane & 31;

    // 4 query column-fragments (128 queries/block, same for all waves)
    float cq[4];
    f16x8 bq[4];
#pragma unroll
    for (int f = 0; f < 4; ++f) {
        const int q = blockIdx.x * QPB + f * 32 + col;
        const float x = Q[q * 3 + 0], y = Q[q * 3 + 1], zc = Q[q * 3 + 2];
        cq[f] = 0.5f * fmaf(zc, zc, fmaf(y, y, x * x));
        bq[f] = make_qfrag(x, y, zc, half);
    }

    const f32x16 zf = (f32x16)0.0f;     // persistent zero C-operand
    float run[4] = {-3.4e38f, -3.4e38f, -3.4e38f, -3.4e38f};

    // wave-private tile range; frag load is lane-linear (16B/lane, 1KB/wave)
    const f16x8* wbase = fr + (size_t)w * (TILES * 64);
    f16x8 a = wbase[lane];
#pragma unroll 4
    for (int t = 0; t < TILES; ++t) {
        f16x8 an;
        if (t + 1 < TILES) an = wbase[(t + 1) * 64 + lane];  // prefetch
#pragma unroll
        for (int f = 0; f < 4; ++f) {
            const f32x16 acc =
                __builtin_amdgcn_mfma_f32_32x32x16_f16(a, bq[f], zf, 0, 0, 0);
            run[f] = merge16(run[f], acc);
        }
        a = an;
    }

    // cross-wave combine: LDS atomicMin on d^2/2 bit patterns (>=0 so uint
    // order == float order). 8 waves x 2 halves per (f,col) slot.
    __shared__ unsigned int smin[QPB];
    __shared__ float psum[2];
    if (tid < QPB) smin[tid] = 0xFFFFFFFFu;
    __syncthreads();
#pragma unroll
    for (int f = 0; f < 4; ++f) {
        const float sval = fmaxf(cq[f] - run[f], 0.0f);
        atomicMin(&smin[f * 32 + col], __float_as_uint(sval));
    }
    __syncthreads();
    if (tid < QPB) {   // waves 0-1: sqrt + mean + per-wave partial sums
        const float v = __uint_as_float(smin[tid]);
        float term = sqrtf(2.0f * v) * (1.0f / NPTS);
#pragma unroll
        for (int off = 32; off > 0; off >>= 1)
            term += __shfl_down(term, off, 64);
        if ((tid & 63) == 0) psum[tid >> 6] = term;
    }
    __syncthreads();
    if (tid == 0) atomicAdd(out, psum[0] + psum[1]);
}

// ---- fallback (proven round-3 VALU path, general shapes) ----
__global__ __launch_bounds__(256) void chamfer_nn_valu(
    const float* __restrict__ A, const float* __restrict__ Bp,
    unsigned int* __restrict__ minA, unsigned int* __restrict__ minB,
    int N, int M, int B)
{
    const int bz = blockIdx.z, b = bz % B, dir = bz / B;
    const float* Q = dir ? Bp : A;
    const float* R = dir ? A : Bp;
    unsigned int* om = dir ? minB : minA;
    const int NQ = dir ? M : N, NR = dir ? N : M;
    const int mSlice = NR / gridDim.y;
    const int tid = threadIdx.x;
    const int nBase = blockIdx.x * (256 * 4);
    const int mStart = blockIdx.y * mSlice;
    const float* qb = Q + (size_t)b * NQ * 3;
    const float* rb = R + (size_t)b * NR * 3;
    float qx[4], qy[4], qz[4], dmax[4];
#pragma unroll
    for (int k = 0; k < 4; ++k) {
        const int n = nBase + tid + k * 256;
        qx[k] = qb[n * 3]; qy[k] = qb[n * 3 + 1]; qz[k] = qb[n * 3 + 2];
        dmax[k] = -3.4e38f;
    }
    __shared__ float4 tgtl[256];
    for (int m0 = mStart; m0 < mStart + mSlice; m0 += 256) {
        __syncthreads();
        {
            const float* src = rb + (size_t)(m0 + tid) * 3;
            const float rx = src[0], ry = src[1], rz = src[2];
            tgtl[tid] = make_float4(rx, ry, rz,
                -0.5f * fmaf(rz, rz, fmaf(ry, ry, rx * rx)));
        }
        __syncthreads();
#pragma unroll 2
        for (int j = 0; j < 256; j += 2) {
            const float4 r0 = tgtl[j], r1 = tgtl[j + 1];
#pragma unroll
            for (int k = 0; k < 4; ++k) {
                const float t0 = fmaf(qz[k], r0.z, fmaf(qy[k], r0.y, fmaf(qx[k], r0.x, r0.w)));
                const float t1 = fmaf(qz[k], r1.z, fmaf(qy[k], r1.y, fmaf(qx[k], r1.x, r1.w)));
                dmax[k] = max3f(dmax[k], t0, t1);
            }
        }
    }
#pragma unroll
    for (int k = 0; k < 4; ++k) {
        const int n = nBase + tid + k * 256;
        const float c = 0.5f * fmaf(qz[k], qz[k], fmaf(qy[k], qy[k], qx[k] * qx[k]));
        atomicMin(&om[(size_t)b * NQ + n], __float_as_uint(fmaxf(c - dmax[k], 0.0f)));
    }
}

__global__ __launch_bounds__(256) void chamfer_reduce(
    const unsigned int* __restrict__ mins, int nA, int nTotal,
    float scaleA, float scaleB, float* __restrict__ out)
{
    float s = 0.0f;
    for (int i = blockIdx.x * blockDim.x + threadIdx.x; i < nTotal;
         i += gridDim.x * blockDim.x) {
        s += sqrtf(2.0f * __uint_as_float(mins[i])) * (i < nA ? scaleA : scaleB);
    }
#pragma unroll
    for (int off = 32; off > 0; off >>= 1) s += __shfl_down(s, off, 64);
    __shared__ float wsum[4];
    const int lane = threadIdx.x & 63, wid = threadIdx.x >> 6;
    if (lane == 0) wsum[wid] = s;
    __syncthreads();
    if (threadIdx.x == 0) atomicAdd(out, wsum[0] + wsum[1] + wsum[2] + wsum[3]);
}

extern "C" void kernel_launch(void* const* d_in, const int* in_sizes, int n_in,
                              void* d_out, int out_size, void* d_ws, size_t ws_size,
                              hipStream_t stream) {
    const float* inp = (const float*)d_in[0];  // [B, N, 3]
    const float* tgt = (const float*)d_in[1];  // [B, M, 3]
    float* out = (float*)d_out;

    const int B = 4, D = 3;
    const int N = in_sizes[0] / (B * D);
    const int M = in_sizes[1] / (B * D);

    const size_t fragBytes = (size_t)8 * FPC * sizeof(f16x8);  // 2 MB

    if (N == NPTS && M == NPTS && B == NB && ws_size >= fragBytes) {
        // ---- prep-once MFMA path: 2 graph nodes (prep zeroes out) ----
        f16x8* frag = (f16x8*)d_ws;
        prep_frags<<<dim3(131072 / 256), 256, 0, stream>>>(inp, tgt, frag, out);
        dim3 grid(NPTS / QPB, 2 * NB);          // (64, 8) = 512 blocks
        chamfer_nn<<<grid, TPB, 0, stream>>>(inp, tgt, frag, out);
    } else {
        // ---- fallback: proven sentinel/atomic VALU path ----
        unsigned int* min_in  = (unsigned int*)d_ws;
        unsigned int* min_tgt = min_in + (size_t)B * N;
        hipMemsetAsync(d_ws, 0xFF,
                       (size_t)(B * N + B * M) * sizeof(unsigned int), stream);
        hipMemsetAsync(d_out, 0, sizeof(float), stream);
        dim3 grid(N / (256 * 4), 32, 2 * B);
        chamfer_nn_valu<<<grid, 256, 0, stream>>>(inp, tgt, min_in, min_tgt, N, M, B);
        chamfer_reduce<<<dim3(64), 256, 0, stream>>>(
            min_in, B * N, B * (N + M), 1.0f / N, 1.0f / M, out);
    }
}